// Round 8
// baseline (271.281 us; speedup 1.0000x reference)
//
#include <hip/hip_runtime.h>
#include <math.h>

// B=16, L=200, H=256, heads=4, d=64
#define LQ 200
#define HDIM 256
#define NROW 3200
#define NBLK 1024     // attn_pass blocks: 4 per CU exactly

// 16-lane sum reduction via DPP adds (VALU pipe).
template <int CTRL>
__device__ __forceinline__ float dpp_add_step(float x) {
    int y = __builtin_amdgcn_update_dpp(0, __float_as_int(x), CTRL, 0xF, 0xF, true);
    return x + __int_as_float(y);
}
__device__ __forceinline__ float reduce16(float x) {
    x = dpp_add_step<0xB1>(x);   // quad_perm xor1
    x = dpp_add_step<0x4E>(x);   // quad_perm xor2
    x = dpp_add_step<0x141>(x);  // row_half_mirror (xor4)
    x = dpp_add_step<0x140>(x);  // row_mirror (xor8)
    return x;
}

// ---------------- Kernel 1: projections + pos-bias folding -------------------
__global__ __launch_bounds__(256) void proj_kernel(
    const float* __restrict__ queries, const float* __restrict__ keys,
    const float* __restrict__ posK, const float* __restrict__ posV,
    const float* __restrict__ Wq, const float* __restrict__ bq,
    const float* __restrict__ Wk, const float* __restrict__ bk,
    const float* __restrict__ Wv, const float* __restrict__ bv,
    float* __restrict__ Qp, float* __restrict__ Ksum, float* __restrict__ Vsum)
{
    __shared__ float qrow[8][HDIM];
    __shared__ float krow[8][HDIM];
    const int t = threadIdx.x;
    const int blk = blockIdx.x;                 // 0..399
    const size_t base = (size_t)blk * 8 * HDIM;

    #pragma unroll
    for (int i = 0; i < 2; ++i) {
        int idx = i * 1024 + t * 4;
        *(float4*)&qrow[0][idx] = *(const float4*)&queries[base + idx];
        *(float4*)&krow[0][idx] = *(const float4*)&keys[base + idx];
    }
    __syncthreads();

    float accQ[8], accK[8], accV[8];
    #pragma unroll
    for (int r = 0; r < 8; ++r) { accQ[r] = 0.f; accK[r] = 0.f; accV[r] = 0.f; }

    const float4* wqp = (const float4*)&Wq[t * HDIM];
    const float4* wkp = (const float4*)&Wk[t * HDIM];
    const float4* wvp = (const float4*)&Wv[t * HDIM];

    for (int k4 = 0; k4 < HDIM / 4; ++k4) {
        float4 wq = wqp[k4], wk = wkp[k4], wv = wvp[k4];
        #pragma unroll
        for (int r = 0; r < 8; ++r) {
            float4 qv = *(const float4*)&qrow[r][k4 * 4];
            float4 kv = *(const float4*)&krow[r][k4 * 4];
            accQ[r] += qv.x * wq.x + qv.y * wq.y + qv.z * wq.z + qv.w * wq.w;
            accK[r] += kv.x * wk.x + kv.y * wk.y + kv.z * wk.z + kv.w * wk.w;
            accV[r] += kv.x * wv.x + kv.y * wv.y + kv.z * wv.z + kv.w * wv.w;
        }
    }

    const float bqv = bq[t], bkv = bk[t], bvv = bv[t];
    #pragma unroll
    for (int r = 0; r < 8; ++r) {
        size_t row = (size_t)blk * 8 + r;
        Qp[row * HDIM + t]   = (accQ[r] + bqv) * 0.125f;   // 1/sqrt(64) folded
        Ksum[row * HDIM + t] = accK[r] + bkv + posK[row * HDIM + t];
        Vsum[row * HDIM + t] = accV[r] + bvv + posV[row * HDIM + t];
    }
}

// ---------------- Kernel 2: per-row unit-count prefix sum -------------------
// Unit = 8 KB of HBM stream: causal row -> 4 keys (tmK+tmV), cnt=ceil((l+1)/4);
// masked row -> 8 keys (tmV only), cnt=25. Upre[0..3200] exclusive prefix.
__global__ __launch_bounds__(256) void scan_kernel(
    const int* __restrict__ tmask, int* __restrict__ Upre)
{
    __shared__ int sh[256];
    const int t = threadIdx.x;
    int carry = 0;
    for (int chunk = 0; chunk < 13; ++chunk) {
        const int idx = chunk * 256 + t;
        int cv = 0;
        if (idx < NROW) {
            const int l = idx % LQ;
            cv = (tmask[idx] != 0) ? (LQ / 8) : ((l + 4) >> 2);
        }
        sh[t] = cv;
        __syncthreads();
        for (int off = 1; off < 256; off <<= 1) {
            int v = (t >= off) ? sh[t - off] : 0;
            __syncthreads();
            sh[t] += v;
            __syncthreads();
        }
        if (idx < NROW) Upre[idx] = carry + sh[t] - cv;   // exclusive
        carry += sh[255];
        __syncthreads();
    }
    if (t == 0) Upre[NROW] = carry;
}

// ---------------- Kernel 3: equal-work streaming attention ------------------
// 1024 blocks x 256 thr, 4 blocks/CU exactly. Block b processes the
// contiguous unit range [b*U/1024, (b+1)*U/1024): identical byte count per
// block, zero tail, near-contiguous memory walk. Wave w handles key
// m = 4k+w (causal) or m = 8k+w / 8k+4+w (masked). Partial (acc, S) per
// touched row flushed by atomicAdd into L2-resident pacc/pS.
__global__ __launch_bounds__(256, 4) void attn_pass(
    const float* __restrict__ Qp, const float* __restrict__ Ksum,
    const float* __restrict__ Vsum, const float* __restrict__ tmK,
    const float* __restrict__ tmV, const int* __restrict__ tmask,
    const int* __restrict__ Upre, float* __restrict__ pacc,
    float* __restrict__ pS)
{
    const int t = threadIdx.x;
    const int w = t >> 6;
    const int ln = t & 63;
    const int h = ln >> 4;
    const int c = ln * 4;
    const int bid0 = blockIdx.x;
    const int bid = (bid0 & 7) * (NBLK / 8) + (bid0 >> 3);  // XCD-contiguous
    const int U = Upre[NROW];
    const long s0 = ((long)bid * U) / NBLK;
    const long s1 = ((long)(bid + 1) * U) / NBLK;
    if (s0 >= s1) return;

    // binary search: largest row with Upre[row] <= s0
    int lo = 0, hi = NROW;
    while (lo + 1 < hi) {
        const int mid = (lo + hi) >> 1;
        if (Upre[mid] <= (int)s0) lo = mid; else hi = mid;
    }
    int row = lo;
    long u = s0;

    while (u < s1) {
        const int rbase = Upre[row];
        const int rcnt  = Upre[row + 1] - rbase;
        const int ku0 = (int)(u - rbase);
        int ku1 = rcnt;
        { const long rem = (s1 - u) + ku0; if (rem < (long)ku1) ku1 = (int)rem; }

        const int b = row / LQ;
        const int l = row - b * LQ;
        const float* tV = tmV + (size_t)row * (LQ * HDIM);
        const float* VS = Vsum + (size_t)b * (LQ * HDIM);

        float4 acc = {0.f, 0.f, 0.f, 0.f};
        float S = 0.f;

        if (tmask[row] != 0) {
            // masked row: e = 1 for all keys; unit k = keys 8k..8k+7
            for (int k = ku0; k < ku1; ++k) {
                const int m = 8 * k + w;
                const size_t o0 = (size_t)m * HDIM + c;
                const size_t o1 = o0 + 4 * HDIM;
                const float4 a0 = *(const float4*)&tV[o0];
                const float4 b0 = *(const float4*)&VS[o0];
                const float4 a1 = *(const float4*)&tV[o1];
                const float4 b1 = *(const float4*)&VS[o1];
                acc.x += (a0.x + b0.x) + (a1.x + b1.x);
                acc.y += (a0.y + b0.y) + (a1.y + b1.y);
                acc.z += (a0.z + b0.z) + (a1.z + b1.z);
                acc.w += (a0.w + b0.w) + (a1.w + b1.w);
                S += 2.f;
            }
        } else {
            // causal row: unit k = keys 4k..4k+3 (clipped at l)
            const float* tK = tmK + (size_t)row * (LQ * HDIM);
            const float* KS = Ksum + (size_t)b * (LQ * HDIM);
            const float4 Q4 = *(const float4*)&Qp[(size_t)row * HDIM + c];
            for (int k = ku0; k < ku1; ++k) {
                const int m = 4 * k + w;
                if (m <= l) {
                    const size_t o = (size_t)m * HDIM + c;
                    const float4 k1v = *(const float4*)&tK[o];
                    const float4 k2v = *(const float4*)&KS[o];
                    float p = Q4.x * (k1v.x + k2v.x) + Q4.y * (k1v.y + k2v.y)
                            + Q4.z * (k1v.z + k2v.z) + Q4.w * (k1v.w + k2v.w);
                    p = reduce16(p);
                    const float e = __expf(p);
                    const float4 v1 = *(const float4*)&tV[o];
                    const float4 v2 = *(const float4*)&VS[o];
                    acc.x += e * (v1.x + v2.x);
                    acc.y += e * (v1.y + v2.y);
                    acc.z += e * (v1.z + v2.z);
                    acc.w += e * (v1.w + v2.w);
                    S += e;
                }
            }
        }

        // flush this row's partial
        float* pr = pacc + (size_t)row * HDIM + c;
        atomicAdd(pr + 0, acc.x);
        atomicAdd(pr + 1, acc.y);
        atomicAdd(pr + 2, acc.z);
        atomicAdd(pr + 3, acc.w);
        if ((ln & 15) == 0) atomicAdd(&pS[row * 4 + h], S);

        u += (ku1 - ku0);
        ++row;
    }
}

// ---------------- Kernel 4: normalize ---------------------------------------
__global__ __launch_bounds__(256) void combine_kernel(
    const float* __restrict__ pacc, const float* __restrict__ pS,
    float* __restrict__ out)
{
    const int row = blockIdx.x;
    const int t = threadIdx.x;
    out[(size_t)row * HDIM + t] =
        pacc[(size_t)row * HDIM + t] / pS[row * 4 + (t >> 6)];
}

// ---------------- launch ----------------------------------------------------
extern "C" void kernel_launch(void* const* d_in, const int* in_sizes, int n_in,
                              void* d_out, int out_size, void* d_ws, size_t ws_size,
                              hipStream_t stream) {
    const float* queries = (const float*)d_in[0];
    const float* keys    = (const float*)d_in[1];
    const int*   tmask   = (const int*)d_in[2];
    // d_in[3] attn_mask: deterministic causal triu(k=1) -> handled analytically
    const float* tmK  = (const float*)d_in[4];
    const float* tmV  = (const float*)d_in[5];
    const float* posK = (const float*)d_in[6];
    const float* posV = (const float*)d_in[7];
    const float* Wq = (const float*)d_in[8];
    const float* bq = (const float*)d_in[9];
    const float* Wk = (const float*)d_in[10];
    const float* bk = (const float*)d_in[11];
    const float* Wv = (const float*)d_in[12];
    const float* bv = (const float*)d_in[13];

    float* ws   = (float*)d_ws;
    float* Qp   = ws;                        // 819,200 floats
    float* Ksum = ws + 819200;               // 819,200
    float* Vsum = ws + 2 * 819200;           // 819,200
    float* pacc = ws + 3 * 819200;           // 3200*256 = 819,200
    float* pS   = ws + 4 * 819200;           // 3200*4 = 12,800
    int*   Upre = (int*)(ws + 4 * 819200 + 12800);  // 3201 ints
    float* out  = (float*)d_out;

    // zero the accumulators (pacc and pS are contiguous)
    hipMemsetAsync(pacc, 0, (size_t)(819200 + 12800) * sizeof(float), stream);

    hipLaunchKernelGGL(proj_kernel, dim3(400), dim3(256), 0, stream,
                       queries, keys, posK, posV, Wq, bq, Wk, bk, Wv, bv,
                       Qp, Ksum, Vsum);
    hipLaunchKernelGGL(scan_kernel, dim3(1), dim3(256), 0, stream,
                       tmask, Upre);
    hipLaunchKernelGGL(attn_pass, dim3(NBLK), dim3(256), 0, stream,
                       Qp, Ksum, Vsum, tmK, tmV, tmask, Upre, pacc, pS);
    hipLaunchKernelGGL(combine_kernel, dim3(NROW), dim3(256), 0, stream,
                       pacc, pS, out);
}

// Round 9
// 245.224 us; speedup vs baseline: 1.1063x; 1.1063x over previous
//
#include <hip/hip_runtime.h>
#include <math.h>

// B=16, L=200, H=256, heads=4, d=64
#define LQ 200
#define HDIM 256
#define CHK 8      // keys per staged chunk (8 KB per tile)

// ---- global -> LDS direct DMA, 16 B per lane (global_load_lds_dwordx4) ----
// LDS dest: wave-uniform base, HW writes lane i at base + i*16 (linear).
// Global src: per-lane address. Layouts here are exactly linear both sides.
__device__ __forceinline__ void gload_lds16(const float* g, float* l) {
    __builtin_amdgcn_global_load_lds(
        (const __attribute__((address_space(1))) void*)g,
        (__attribute__((address_space(3))) void*)l, 16, 0, 0);
}

// 16-lane sum reduction via DPP adds (VALU pipe).
template <int CTRL>
__device__ __forceinline__ float dpp_add_step(float x) {
    int y = __builtin_amdgcn_update_dpp(0, __float_as_int(x), CTRL, 0xF, 0xF, true);
    return x + __int_as_float(y);
}
__device__ __forceinline__ float reduce16(float x) {
    x = dpp_add_step<0xB1>(x);   // quad_perm xor1
    x = dpp_add_step<0x4E>(x);   // quad_perm xor2
    x = dpp_add_step<0x141>(x);  // row_half_mirror (xor4)
    x = dpp_add_step<0x140>(x);  // row_mirror (xor8)
    return x;
}

// ---------------- Kernel 1: projections + pos-bias folding -------------------
__global__ __launch_bounds__(256) void proj_kernel(
    const float* __restrict__ queries, const float* __restrict__ keys,
    const float* __restrict__ posK, const float* __restrict__ posV,
    const float* __restrict__ Wq, const float* __restrict__ bq,
    const float* __restrict__ Wk, const float* __restrict__ bk,
    const float* __restrict__ Wv, const float* __restrict__ bv,
    float* __restrict__ Qp, float* __restrict__ Ksum, float* __restrict__ Vsum)
{
    __shared__ float qrow[8][HDIM];
    __shared__ float krow[8][HDIM];
    const int t = threadIdx.x;
    const int blk = blockIdx.x;                 // 0..399
    const size_t base = (size_t)blk * 8 * HDIM;

    #pragma unroll
    for (int i = 0; i < 2; ++i) {
        int idx = i * 1024 + t * 4;
        *(float4*)&qrow[0][idx] = *(const float4*)&queries[base + idx];
        *(float4*)&krow[0][idx] = *(const float4*)&keys[base + idx];
    }
    __syncthreads();

    float accQ[8], accK[8], accV[8];
    #pragma unroll
    for (int r = 0; r < 8; ++r) { accQ[r] = 0.f; accK[r] = 0.f; accV[r] = 0.f; }

    const float4* wqp = (const float4*)&Wq[t * HDIM];
    const float4* wkp = (const float4*)&Wk[t * HDIM];
    const float4* wvp = (const float4*)&Wv[t * HDIM];

    for (int k4 = 0; k4 < HDIM / 4; ++k4) {
        float4 wq = wqp[k4], wk = wkp[k4], wv = wvp[k4];
        #pragma unroll
        for (int r = 0; r < 8; ++r) {
            float4 qv = *(const float4*)&qrow[r][k4 * 4];
            float4 kv = *(const float4*)&krow[r][k4 * 4];
            accQ[r] += qv.x * wq.x + qv.y * wq.y + qv.z * wq.z + qv.w * wq.w;
            accK[r] += kv.x * wk.x + kv.y * wk.y + kv.z * wk.z + kv.w * wk.w;
            accV[r] += kv.x * wv.x + kv.y * wv.y + kv.z * wv.z + kv.w * wv.w;
        }
    }

    const float bqv = bq[t], bkv = bk[t], bvv = bv[t];
    #pragma unroll
    for (int r = 0; r < 8; ++r) {
        size_t row = (size_t)blk * 8 + r;
        Qp[row * HDIM + t]   = (accQ[r] + bqv) * 0.125f;   // 1/sqrt(64) folded
        Ksum[row * HDIM + t] = accK[r] + bkv + posK[row * HDIM + t];
        Vsum[row * HDIM + t] = accV[r] + bvv + posV[row * HDIM + t];
    }
}

// ---------------- Kernel 2: DMA-staged fused attention ----------------------
// Block per (b,l) row. Per 8-key chunk: DMA tmV (+tmK if causal) tile into
// double-buffered LDS via global_load_lds (16 KB burst in flight, no VGPR
// return, no dependent compute between issues). One __syncthreads per chunk
// (its vmcnt(0)+lgkmcnt(0) drain is the DMA completion wait). Compute of
// chunk ch overlaps the DMA of chunk ch+1. Wave w owns keys mm = w, w+4 of
// each chunk; KS/VS stay direct (L2-resident) float4 loads.
__global__ __launch_bounds__(256) void attn_dma(
    const float* __restrict__ Qp, const float* __restrict__ Ksum,
    const float* __restrict__ Vsum, const float* __restrict__ tmK,
    const float* __restrict__ tmV, const int* __restrict__ tmask,
    float* __restrict__ out)
{
    __shared__ float kt[2][CHK][HDIM];   // 16 KB
    __shared__ float vt[2][CHK][HDIM];   // 16 KB
    __shared__ float outp[4][HDIM];      // 4 KB
    __shared__ float Ssh[4][4];

    const int t = threadIdx.x;
    const int w = t >> 6;
    const int ln = t & 63;
    const int h = ln >> 4;
    const int c = ln * 4;
    const int blk = blockIdx.x;       // b*200 + l
    const int b = blk / LQ;
    const int l = blk - b * LQ;

    const bool rowmask = (tmask[blk] != 0);
    const size_t rowsz = (size_t)LQ * HDIM;
    const float* tVr = tmV + (size_t)blk * rowsz;
    const float* tKr = tmK + (size_t)blk * rowsz;
    const float* KS  = Ksum + (size_t)b * rowsz;
    const float* VS  = Vsum + (size_t)b * rowsz;
    // masked: all 200 keys (A exactly uniform); causal: keys 0..l (A=0 beyond)
    const int nkeys = rowmask ? LQ : (l + 1);
    const int nch = (nkeys + CHK - 1) / CHK;  // stage may over-read <=7 keys
                                              // within the row (valid memory)

    const float4 Q4 = *(const float4*)&Qp[(size_t)blk * HDIM + c];

    // wave w DMAs key-rows j = 2w, 2w+1 of each 8-key tile (1 KB per instr)
    auto stage = [&](int buf, int ch) {
        const int j0 = 2 * w;
        const size_t base = (size_t)(ch * CHK) * HDIM + (size_t)ln * 4;
        gload_lds16(tVr + base + (size_t)j0 * HDIM,       &vt[buf][j0][0]);
        gload_lds16(tVr + base + (size_t)(j0 + 1) * HDIM, &vt[buf][j0 + 1][0]);
        if (!rowmask) {
            gload_lds16(tKr + base + (size_t)j0 * HDIM,       &kt[buf][j0][0]);
            gload_lds16(tKr + base + (size_t)(j0 + 1) * HDIM, &kt[buf][j0 + 1][0]);
        }
    };

    float4 acc = {0.f, 0.f, 0.f, 0.f};
    float S = 0.f;

    stage(0, 0);
    __syncthreads();                       // DMA chunk0 complete
    int cur = 0;
    for (int ch = 0; ch < nch; ++ch) {
        if (ch + 1 < nch) stage(cur ^ 1, ch + 1);   // next burst in flight
        #pragma unroll
        for (int q = 0; q < 2; ++q) {
            const int mm = w + 4 * q;
            const int m = ch * CHK + mm;
            if (m < nkeys) {               // wave-uniform predicate
                const float4 v1 = *(const float4*)&vt[cur][mm][c];
                const float4 v2 = *(const float4*)&VS[(size_t)m * HDIM + c];
                float e;
                if (rowmask) {
                    e = 1.0f;              // exact uniform softmax row
                } else {
                    const float4 k1 = *(const float4*)&kt[cur][mm][c];
                    const float4 k2 = *(const float4*)&KS[(size_t)m * HDIM + c];
                    float p = Q4.x * (k1.x + k2.x) + Q4.y * (k1.y + k2.y)
                            + Q4.z * (k1.z + k2.z) + Q4.w * (k1.w + k2.w);
                    p = reduce16(p);
                    e = __expf(p);         // no max-subtract: |s| <~ 8
                }
                acc.x += e * (v1.x + v2.x);
                acc.y += e * (v1.y + v2.y);
                acc.z += e * (v1.z + v2.z);
                acc.w += e * (v1.w + v2.w);
                S += e;
            }
        }
        __syncthreads();                   // drain next-chunk DMA + reuse guard
        cur ^= 1;
    }

    *(float4*)&outp[w][c] = acc;
    if ((ln & 15) == 0) Ssh[w][h] = S;
    __syncthreads();

    const int hh = t >> 6;                 // head owning output channel t
    const float Stot = Ssh[0][hh] + Ssh[1][hh] + Ssh[2][hh] + Ssh[3][hh];
    out[(size_t)blk * HDIM + t] =
        (outp[0][t] + outp[1][t] + outp[2][t] + outp[3][t]) / Stot;
}

// ---------------- launch ----------------------------------------------------
extern "C" void kernel_launch(void* const* d_in, const int* in_sizes, int n_in,
                              void* d_out, int out_size, void* d_ws, size_t ws_size,
                              hipStream_t stream) {
    const float* queries = (const float*)d_in[0];
    const float* keys    = (const float*)d_in[1];
    const int*   tmask   = (const int*)d_in[2];
    // d_in[3] attn_mask: deterministic causal triu(k=1) -> handled analytically
    const float* tmK  = (const float*)d_in[4];
    const float* tmV  = (const float*)d_in[5];
    const float* posK = (const float*)d_in[6];
    const float* posV = (const float*)d_in[7];
    const float* Wq = (const float*)d_in[8];
    const float* bq = (const float*)d_in[9];
    const float* Wk = (const float*)d_in[10];
    const float* bk = (const float*)d_in[11];
    const float* Wv = (const float*)d_in[12];
    const float* bv = (const float*)d_in[13];

    float* ws   = (float*)d_ws;
    float* Qp   = ws;                  // 819,200 floats
    float* Ksum = ws + 819200;         // 819,200
    float* Vsum = ws + 2 * 819200;     // 819,200
    float* out  = (float*)d_out;

    hipLaunchKernelGGL(proj_kernel, dim3(400), dim3(256), 0, stream,
                       queries, keys, posK, posV, Wq, bq, Wk, bk, Wv, bv,
                       Qp, Ksum, Vsum);
    hipLaunchKernelGGL(attn_dma, dim3(3200), dim3(256), 0, stream,
                       Qp, Ksum, Vsum, tmK, tmV, tmask, out);
}

// Round 10
// 227.864 us; speedup vs baseline: 1.1905x; 1.0762x over previous
//
#include <hip/hip_runtime.h>
#include <math.h>

// B=16, L=200, H=256, heads=4, d=64
#define LQ 200
#define HDIM 256

// 16-lane sum reduction via DPP adds (VALU pipe, no LDS traffic).
template <int CTRL>
__device__ __forceinline__ float dpp_add_step(float x) {
    int y = __builtin_amdgcn_update_dpp(0, __float_as_int(x), CTRL, 0xF, 0xF, true);
    return x + __int_as_float(y);
}
__device__ __forceinline__ float reduce16(float x) {
    x = dpp_add_step<0xB1>(x);   // quad_perm xor1
    x = dpp_add_step<0x4E>(x);   // quad_perm xor2
    x = dpp_add_step<0x141>(x);  // row_half_mirror (xor4)
    x = dpp_add_step<0x140>(x);  // row_mirror (xor8)
    return x;
}

// ---------------- Kernel 1: projections + pos-bias folding -------------------
__global__ __launch_bounds__(256) void proj_kernel(
    const float* __restrict__ queries, const float* __restrict__ keys,
    const float* __restrict__ posK, const float* __restrict__ posV,
    const float* __restrict__ Wq, const float* __restrict__ bq,
    const float* __restrict__ Wk, const float* __restrict__ bk,
    const float* __restrict__ Wv, const float* __restrict__ bv,
    float* __restrict__ Qp, float* __restrict__ Ksum, float* __restrict__ Vsum)
{
    __shared__ float qrow[8][HDIM];
    __shared__ float krow[8][HDIM];
    const int t = threadIdx.x;
    const int blk = blockIdx.x;                 // 0..399
    const size_t base = (size_t)blk * 8 * HDIM;

    #pragma unroll
    for (int i = 0; i < 2; ++i) {
        int idx = i * 1024 + t * 4;
        *(float4*)&qrow[0][idx] = *(const float4*)&queries[base + idx];
        *(float4*)&krow[0][idx] = *(const float4*)&keys[base + idx];
    }
    __syncthreads();

    float accQ[8], accK[8], accV[8];
    #pragma unroll
    for (int r = 0; r < 8; ++r) { accQ[r] = 0.f; accK[r] = 0.f; accV[r] = 0.f; }

    const float4* wqp = (const float4*)&Wq[t * HDIM];
    const float4* wkp = (const float4*)&Wk[t * HDIM];
    const float4* wvp = (const float4*)&Wv[t * HDIM];

    for (int k4 = 0; k4 < HDIM / 4; ++k4) {
        float4 wq = wqp[k4], wk = wkp[k4], wv = wvp[k4];
        #pragma unroll
        for (int r = 0; r < 8; ++r) {
            float4 qv = *(const float4*)&qrow[r][k4 * 4];
            float4 kv = *(const float4*)&krow[r][k4 * 4];
            accQ[r] += qv.x * wq.x + qv.y * wq.y + qv.z * wq.z + qv.w * wq.w;
            accK[r] += kv.x * wk.x + kv.y * wk.y + kv.z * wk.z + kv.w * wk.w;
            accV[r] += kv.x * wv.x + kv.y * wv.y + kv.z * wv.z + kv.w * wv.w;
        }
    }

    const float bqv = bq[t], bkv = bk[t], bvv = bv[t];
    #pragma unroll
    for (int r = 0; r < 8; ++r) {
        size_t row = (size_t)blk * 8 + r;
        Qp[row * HDIM + t]   = (accQ[r] + bqv) * 0.125f;   // 1/sqrt(64) folded
        Ksum[row * HDIM + t] = accK[r] + bkv + posK[row * HDIM + t];
        Vsum[row * HDIM + t] = accV[r] + bvv + posV[row * HDIM + t];
    }
}

// ---------------- Kernel 2: fused single-pass attention, LPT order ----------
// Block slot -> row mapping is LONGEST-FIRST: l = 199 - slot/16, b = slot%16.
// Big blocks (l high: up to 400 KB of stream) dispatch first; the ~1100
// backfilled blocks are all small -> near-optimal makespan (LPT scheduling).
// Body identical to R5: wave w owns keys m == w (mod 4); masked rows skip
// tmK and use exact-uniform A; causal rows clip at l; exp w/o max-subtract;
// 1-ahead register prefetch.
__global__ __launch_bounds__(256) void attn_fused(
    const float* __restrict__ Qp, const float* __restrict__ Ksum,
    const float* __restrict__ Vsum, const float* __restrict__ tmK,
    const float* __restrict__ tmV, const int* __restrict__ tmask,
    float* __restrict__ out)
{
    __shared__ float outp[4][HDIM];   // per-wave output partials
    __shared__ float Ssh[4][4];       // per-wave, per-head softmax denoms

    const int t = threadIdx.x;
    const int w = t >> 6;
    const int ln = t & 63;
    const int h = ln >> 4;
    const int c = ln * 4;
    // LPT (longest-first) static order
    const int slot = blockIdx.x;          // 0..3199
    const int l = (LQ - 1) - (slot >> 4); // 199 down to 0
    const int b = slot & 15;
    const int blk = b * LQ + l;

    const bool rowmask = (tmask[blk] != 0);

    const float* pTV = tmV + (size_t)blk * (LQ * HDIM) + w * HDIM;
    const float* pVS = Vsum + (size_t)b * (LQ * HDIM) + w * HDIM;

    float4 acc = {0.f, 0.f, 0.f, 0.f};

    if (rowmask) {
        // ---- exact-uniform row: out = (1/200) * sum_m (Vsum[m] + tmV[m]) ----
        float4 a0 = *(const float4*)&pTV[c];
        float4 b0 = *(const float4*)&pVS[c];
        float4 a1 = *(const float4*)&pTV[4 * HDIM + c];
        float4 b1 = *(const float4*)&pVS[4 * HDIM + c];
        for (int i = 1; i < LQ / 8; ++i) {
            pTV += 8 * HDIM;
            pVS += 8 * HDIM;
            const float4 na0 = *(const float4*)&pTV[c];
            const float4 nb0 = *(const float4*)&pVS[c];
            const float4 na1 = *(const float4*)&pTV[4 * HDIM + c];
            const float4 nb1 = *(const float4*)&pVS[4 * HDIM + c];
            acc.x += (a0.x + b0.x) + (a1.x + b1.x);
            acc.y += (a0.y + b0.y) + (a1.y + b1.y);
            acc.z += (a0.z + b0.z) + (a1.z + b1.z);
            acc.w += (a0.w + b0.w) + (a1.w + b1.w);
            a0 = na0; b0 = nb0; a1 = na1; b1 = nb1;
        }
        acc.x += (a0.x + b0.x) + (a1.x + b1.x);
        acc.y += (a0.y + b0.y) + (a1.y + b1.y);
        acc.z += (a0.z + b0.z) + (a1.z + b1.z);
        acc.w += (a0.w + b0.w) + (a1.w + b1.w);

        *(float4*)&outp[w][c] = acc;
        __syncthreads();
        out[(size_t)blk * HDIM + t] =
            (outp[0][t] + outp[1][t] + outp[2][t] + outp[3][t]) * (1.0f / LQ);
    } else {
        // ---- causal row: m in [0, l], this wave: m = w, w+4, ... ----
        const float* pTK = tmK + (size_t)blk * (LQ * HDIM) + w * HDIM;
        const float* pKS = Ksum + (size_t)b * (LQ * HDIM) + w * HDIM;
        const float4 Q4 = *(const float4*)&Qp[(size_t)blk * HDIM + c];
        const int n = (l >= w) ? ((l - w) >> 2) + 1 : 0;
        float S = 0.f;

        if (n > 0) {
            float4 k1 = *(const float4*)&pTK[c];
            float4 k2 = *(const float4*)&pKS[c];
            float4 v1 = *(const float4*)&pTV[c];
            float4 v2 = *(const float4*)&pVS[c];
            for (int i = 1; i < n; ++i) {
                pTK += 4 * HDIM; pKS += 4 * HDIM;
                pTV += 4 * HDIM; pVS += 4 * HDIM;
                const float4 nk1 = *(const float4*)&pTK[c];
                const float4 nk2 = *(const float4*)&pKS[c];
                const float4 nv1 = *(const float4*)&pTV[c];
                const float4 nv2 = *(const float4*)&pVS[c];
                float p = Q4.x * (k1.x + k2.x) + Q4.y * (k1.y + k2.y)
                        + Q4.z * (k1.z + k2.z) + Q4.w * (k1.w + k2.w);
                p = reduce16(p);
                const float e = __expf(p);
                acc.x += e * (v1.x + v2.x);
                acc.y += e * (v1.y + v2.y);
                acc.z += e * (v1.z + v2.z);
                acc.w += e * (v1.w + v2.w);
                S += e;
                k1 = nk1; k2 = nk2; v1 = nv1; v2 = nv2;
            }
            float p = Q4.x * (k1.x + k2.x) + Q4.y * (k1.y + k2.y)
                    + Q4.z * (k1.z + k2.z) + Q4.w * (k1.w + k2.w);
            p = reduce16(p);
            const float e = __expf(p);
            acc.x += e * (v1.x + v2.x);
            acc.y += e * (v1.y + v2.y);
            acc.z += e * (v1.z + v2.z);
            acc.w += e * (v1.w + v2.w);
            S += e;
        }

        *(float4*)&outp[w][c] = acc;
        if ((ln & 15) == 0) Ssh[w][h] = S;
        __syncthreads();

        const int hh = t >> 6;   // head owning output channel t
        const float Stot = Ssh[0][hh] + Ssh[1][hh] + Ssh[2][hh] + Ssh[3][hh];
        out[(size_t)blk * HDIM + t] =
            (outp[0][t] + outp[1][t] + outp[2][t] + outp[3][t]) / Stot;
    }
}

// ---------------- launch ----------------------------------------------------
extern "C" void kernel_launch(void* const* d_in, const int* in_sizes, int n_in,
                              void* d_out, int out_size, void* d_ws, size_t ws_size,
                              hipStream_t stream) {
    const float* queries = (const float*)d_in[0];
    const float* keys    = (const float*)d_in[1];
    const int*   tmask   = (const int*)d_in[2];
    // d_in[3] attn_mask: deterministic causal triu(k=1) -> handled analytically
    const float* tmK  = (const float*)d_in[4];
    const float* tmV  = (const float*)d_in[5];
    const float* posK = (const float*)d_in[6];
    const float* posV = (const float*)d_in[7];
    const float* Wq = (const float*)d_in[8];
    const float* bq = (const float*)d_in[9];
    const float* Wk = (const float*)d_in[10];
    const float* bk = (const float*)d_in[11];
    const float* Wv = (const float*)d_in[12];
    const float* bv = (const float*)d_in[13];

    float* ws   = (float*)d_ws;
    float* Qp   = ws;                  // 819,200 floats
    float* Ksum = ws + 819200;         // 819,200
    float* Vsum = ws + 2 * 819200;     // 819,200
    float* out  = (float*)d_out;

    hipLaunchKernelGGL(proj_kernel, dim3(400), dim3(256), 0, stream,
                       queries, keys, posK, posV, Wq, bq, Wk, bk, Wv, bv,
                       Qp, Ksum, Vsum);
    hipLaunchKernelGGL(attn_fused, dim3(3200), dim3(256), 0, stream,
                       Qp, Ksum, Vsum, tmK, tmV, tmask, out);
}